// Round 5
// baseline (95.219 us; speedup 1.0000x reference)
//
#include <hip/hip_runtime.h>
#include <hip/hip_bf16.h>

// Problem constants (fixed by setup_inputs):
//   T=36, Q=2048, C=42 (num_classes=41), N=128
// Inputs (d_in order):
//   0: pred_logits  float32 [T*Q, C]
//   1: pred_boxes   float32 [T*Q, 4]   (cx,cy,w,h)
//   2: tgt_labels   int32   [N*T]
//   3: tgt_boxes    float32 [N*T, 4]
//   4: tgt_valid    int32   [N*T]
//   5: tgt_original_valid int32 [N*T]
// Output: float32 [Q, N] row-major, out[q*N+n]
//
// R5 structure: ONE fused kernel (grid = 32 q-tiles x 36 t) keeps softmax
// probs in LDS (P2 never materialized; logits read exactly once; pred_boxes
// read once per (q,t) instead of once per (q,t,n-block)); per-t cost terms
// accumulate via coalesced hardware-fadd atomics into ws2[n][q] (n-major so
// lane=q gives 256B/wave atomics). finalize transposes to out[q][n] and
// applies 1/denom AFTER the sum (matches reference order).

constexpr int T = 36;
constexpr int Q = 2048;
constexpr int C = 42;
constexpr int N = 128;

// ---------------------------------------------------------------------------
// Zero ws2 (N*Q floats = 1 MB). ws is re-poisoned 0xAA before every call.
// ---------------------------------------------------------------------------
__global__ __launch_bounds__(256) void zero_ws_kernel(float4* __restrict__ ws2) {
  ws2[blockIdx.x * 256 + threadIdx.x] = make_float4(0.f, 0.f, 0.f, 0.f);
}

// ---------------------------------------------------------------------------
// Fused softmax + cost. Block 256 = 64 q-lanes x 4 n-subgroups (sub == wave
// id, so (n,t) is wave-uniform in the n-loop -> non-divergent valid-skip).
// ---------------------------------------------------------------------------
__global__ __launch_bounds__(256) void fused_cost_kernel(
    const float* __restrict__ logits, const float* __restrict__ pred_boxes,
    const int* __restrict__ labels, const float* __restrict__ tboxes,
    const int* __restrict__ valid, const int* __restrict__ ovalid,
    float* __restrict__ ws2) {
  constexpr int LS = C + 1;  // 43 = 11 mod 32, gcd(11,32)=1 -> conflict-free

  __shared__ float tile[64 * LS];
  __shared__ float s_max[4 * 64];
  __shared__ float s_sum[4 * 64];
  __shared__ float s_rinv[64];
  __shared__ float4 s_tb[N];
  __shared__ int s_idv[N];  // (valid<<8) | id

  const int t = blockIdx.y;
  const int q0 = blockIdx.x * 64;
  const int tid = threadIdx.x;
  const int lane = tid & 63;  // q offset
  const int sub = tid >> 6;   // wave id
  const int q = q0 + lane;

  // Coalesced load of this (t, q-tile)'s logits: 64 rows x 42 cols.
  const float* src = logits + ((size_t)t * Q + q0) * C;
  for (int i = tid; i < 64 * C; i += 256) {
    tile[(i / C) * LS + (i % C)] = src[i];
  }
  // Target metadata for all 128 n at this t (small, L2-resident).
  if (tid < N) {
    int g = tid * T + t;
    s_idv[tid] = ((ovalid[g] == 0) ? (C - 1) : labels[g]) | (valid[g] << 8);
    s_tb[tid] = ((const float4*)tboxes)[g];
  }
  __syncthreads();

  // Softmax: 4 threads per row, col ranges {0..10, 11..21, 22..31, 32..41}.
  const int part = sub;
  const int row = lane;
  const int c0 = (part < 2) ? part * 11 : 22 + (part - 2) * 10;
  const int c1 = (part < 2) ? c0 + 11 : c0 + 10;

  float m = -1e30f;
  for (int c = c0; c < c1; ++c) m = fmaxf(m, tile[row * LS + c]);
  s_max[part * 64 + row] = m;
  __syncthreads();

  m = fmaxf(fmaxf(s_max[row], s_max[64 + row]),
            fmaxf(s_max[128 + row], s_max[192 + row]));
  float s = 0.f;
  for (int c = c0; c < c1; ++c) {
    float e = __expf(tile[row * LS + c] - m);
    tile[row * LS + c] = e;  // keep exp in the tile; scale at use
    s += e;
  }
  s_sum[part * 64 + row] = s;
  __syncthreads();

  if (part == 0) {
    s_rinv[row] = 1.f / (s_sum[row] + s_sum[64 + row] + s_sum[128 + row] +
                         s_sum[192 + row]);
  }
  __syncthreads();

  const float rinv_l = s_rinv[lane];  // 1/sum for this thread's q-row

  // Pred box for (t,q): ONE coalesced float4 per thread, reused for 32 n.
  float4 pb = ((const float4*)pred_boxes)[t * Q + q];
  const float px1 = pb.x - 0.5f * pb.z, py1 = pb.y - 0.5f * pb.w;
  const float px2 = pb.x + 0.5f * pb.z, py2 = pb.y + 0.5f * pb.w;
  const float pa = pb.z * pb.w;

  for (int i = 0; i < 32; ++i) {
    int n = i * 4 + sub;  // wave-uniform
    int pk = s_idv[n];
    if (pk & 0x100) {  // wave-uniform valid-skip, no divergence
      float4 tb = s_tb[n];  // broadcast
      // LDS "gather": addr = lane*43 + id -> banks lane*11+id mod 32, free.
      float p = tile[lane * LS + (pk & 0xff)] * rinv_l;
      float l1 = 0.25f * (fabsf(pb.x - tb.x) + fabsf(pb.y - tb.y) +
                          fabsf(pb.z - tb.z) + fabsf(pb.w - tb.w));
      float tx1 = tb.x - 0.5f * tb.z, ty1 = tb.y - 0.5f * tb.w;
      float tx2 = tb.x + 0.5f * tb.z, ty2 = tb.y + 0.5f * tb.w;
      float iw = fmaxf(fminf(px2, tx2) - fmaxf(px1, tx1), 0.f);
      float ih = fmaxf(fminf(py2, ty2) - fmaxf(py1, ty1), 0.f);
      float inter = iw * ih;
      float uni = pa + tb.z * tb.w - inter;
      float term = l1 - p - inter / uni;
      // ws2 is [n][q]: lane=q -> 64 consecutive floats = coalesced 256B
      // wave atomic. Hardware global_atomic_add_f32 (device scope).
      unsafeAtomicAdd(&ws2[(size_t)n * Q + q], term);
    }
  }
}

// ---------------------------------------------------------------------------
// Finalize: out[q][n] = ws2[n][q] * (1/denom[n]). Transpose via padded LDS;
// both global accesses coalesced. Grid (Q/64, N/64) = (32, 2).
// ---------------------------------------------------------------------------
__global__ __launch_bounds__(256) void finalize_kernel(
    const float* __restrict__ ws2, const int* __restrict__ valid,
    float* __restrict__ out) {
  __shared__ float s_t[64 * 65];  // pad 65: banks (nl+ql) mod 32, free
  __shared__ float s_rd[64];

  const int q0 = blockIdx.x * 64;
  const int n0 = blockIdx.y * 64;
  const int tid = threadIdx.x;

  if (tid < 64) {
    int n = n0 + tid;
    const int4* vp = (const int4*)(valid + n * T);  // n*T*4 = n*144, 16B-aligned
    int s = 0;
    for (int k = 0; k < T / 4; ++k) {
      int4 v = vp[k];
      s += v.x + v.y + v.z + v.w;
    }
    s_rd[tid] = 1.f / (float)s;
  }
  for (int i = tid; i < 64 * 64; i += 256) {
    int nl = i >> 6, ql = i & 63;  // lanes vary ql -> coalesced ws2 read
    s_t[nl * 65 + ql] = ws2[(size_t)(n0 + nl) * Q + q0 + ql];
  }
  __syncthreads();
  for (int i = tid; i < 64 * 64; i += 256) {
    int ql = i >> 6, nl = i & 63;  // lanes vary nl -> coalesced out write
    out[(size_t)(q0 + ql) * N + n0 + nl] = s_t[nl * 65 + ql] * s_rd[nl];
  }
}

extern "C" void kernel_launch(void* const* d_in, const int* in_sizes, int n_in,
                              void* d_out, int out_size, void* d_ws, size_t ws_size,
                              hipStream_t stream) {
  const float* logits = (const float*)d_in[0];
  const float* pboxes = (const float*)d_in[1];
  const int* labels = (const int*)d_in[2];
  const float* tboxes = (const float*)d_in[3];
  const int* valid = (const int*)d_in[4];
  const int* ovalid = (const int*)d_in[5];
  float* out = (float*)d_out;

  // ws2: accumulator [N][Q] = 262144 floats = 1 MB, n-major for coalesced
  // atomics. Must be zeroed every call (ws re-poisoned 0xAA by harness).
  float* ws2 = (float*)d_ws;

  zero_ws_kernel<<<(N * Q / 4) / 256, 256, 0, stream>>>((float4*)ws2);

  dim3 g(Q / 64, T);
  fused_cost_kernel<<<g, 256, 0, stream>>>(logits, pboxes, labels, tboxes,
                                           valid, ovalid, ws2);

  dim3 gf(Q / 64, N / 64);
  finalize_kernel<<<gf, 256, 0, stream>>>(ws2, valid, out);
}

// Round 6
// 85.693 us; speedup vs baseline: 1.1112x; 1.1112x over previous
//
#include <hip/hip_runtime.h>
#include <hip/hip_bf16.h>

// Problem constants (fixed by setup_inputs):
//   T=36, Q=2048, C=42 (num_classes=41), N=128
// Inputs (d_in order):
//   0: pred_logits  float32 [T*Q, C]
//   1: pred_boxes   float32 [T*Q, 4]   (cx,cy,w,h)
//   2: tgt_labels   int32   [N*T]
//   3: tgt_boxes    float32 [N*T, 4]
//   4: tgt_valid    int32   [N*T]
//   5: tgt_original_valid int32 [N*T]
// Output: float32 [Q, N] row-major, out[q*N+n]
//
// R6 = R4 (best measured: two kernels, valid-skip + t-split) with P2 stored
// as bf16 — halves the inter-kernel traffic (12.4->6.2 MB write, 19->9.4 MB
// gather reads). probs are in [0,1]; bf16 quantization adds <~2e-3 absolute,
// class cost averages ~18 terms -> absmax ~4e-3 vs 8.9e-3 threshold.

constexpr int T = 36;
constexpr int Q = 2048;
constexpr int C = 42;
constexpr int N = 128;

// ---------------------------------------------------------------------------
// Kernel 1: row softmax of logits, written TRANSPOSED as P2[t][c][q] (bf16).
// 4 threads per row in the reduction; exp computed once (stored in tile).
// Write pass pairs two q's per thread -> coalesced 4B bf16x2 stores.
// ---------------------------------------------------------------------------
__global__ __launch_bounds__(256) void softmax_transpose_kernel(
    const float* __restrict__ logits, __hip_bfloat16* __restrict__ P2) {
  constexpr int QB = 64;
  constexpr int LS = C + 1;  // 43: gcd(43,32)=1 -> conflict-free

  __shared__ float tile[QB * LS];
  __shared__ float s_max[4 * QB];
  __shared__ float s_sum[4 * QB];
  __shared__ float s_rinv[QB];

  const int t = blockIdx.y;
  const int q0 = blockIdx.x * QB;
  const int tid = threadIdx.x;

  const float* src = logits + ((size_t)t * Q + q0) * C;
  for (int i = tid; i < QB * C; i += 256) {
    int r = i / C, c = i % C;
    tile[r * LS + c] = src[i];
  }
  __syncthreads();

  // 4 threads per row: col ranges {0..10, 11..21, 22..31, 32..41}.
  const int part = tid >> 6;
  const int row = tid & 63;
  const int c0 = (part < 2) ? part * 11 : 22 + (part - 2) * 10;
  const int c1 = (part < 2) ? c0 + 11 : c0 + 10;

  float m = -1e30f;
  for (int c = c0; c < c1; ++c) m = fmaxf(m, tile[row * LS + c]);
  s_max[part * QB + row] = m;
  __syncthreads();

  m = fmaxf(fmaxf(s_max[row], s_max[QB + row]),
            fmaxf(s_max[2 * QB + row], s_max[3 * QB + row]));
  float s = 0.f;
  for (int c = c0; c < c1; ++c) {
    float e = __expf(tile[row * LS + c] - m);
    tile[row * LS + c] = e;  // single exp: reuse in the write pass
    s += e;
  }
  s_sum[part * QB + row] = s;
  __syncthreads();

  if (part == 0) {
    float stot = s_sum[row] + s_sum[QB + row] + s_sum[2 * QB + row] +
                 s_sum[3 * QB + row];
    s_rinv[row] = 1.f / stot;
  }
  __syncthreads();

  // Transposed write, two q's per thread -> coalesced 4B stores.
  // LDS read banks: (2*r2*43+c) mod 32 stride 22 -> 2-way alias (free).
  for (int i = tid; i < QB * C / 2; i += 256) {
    int c = i >> 5;       // 0..41
    int r2 = i & 31;      // q-pair index
    float v0 = tile[(2 * r2) * LS + c] * s_rinv[2 * r2];
    float v1 = tile[(2 * r2 + 1) * LS + c] * s_rinv[2 * r2 + 1];
    __hip_bfloat162 pk;
    pk.x = __float2bfloat16(v0);
    pk.y = __float2bfloat16(v1);
    *(__hip_bfloat162*)(P2 + (size_t)(t * C + c) * Q + q0 + 2 * r2) = pk;
  }
}

// ---------------------------------------------------------------------------
// Kernel 2: cost[q,n] = sum_t valid*(l1 - prob - iou) / denom[n].
// R4 structure (best measured): wave-uniform valid-skip branch, loads under
// the branch, block = 512 threads = 64 q x 4 n-subs x 2 t-halves (18 t each),
// grid (32,32) = 1024 blocks x 8 waves = 32 waves/CU. bf16 prob gather:
// 64 lanes -> 64 consecutive bf16 = one 128B line.
// ---------------------------------------------------------------------------
__global__ __launch_bounds__(512) void cost_kernel(
    const __hip_bfloat16* __restrict__ P2, const float* __restrict__ pred_boxes,
    const int* __restrict__ labels, const float* __restrict__ tboxes,
    const int* __restrict__ valid, const int* __restrict__ ovalid,
    float* __restrict__ out) {
  constexpr int NB = 4;
  constexpr int RS = NB + 1;  // stride 5: gcd(5,32)=1, conflict-free

  const int q0 = blockIdx.x * 64;
  const int n0 = blockIdx.y * NB;
  const int tid = threadIdx.x;      // 0..511
  const int lane = tid & 63;        // q offset
  const int sub = (tid >> 6) & 3;   // local n (wave-uniform)
  const int half = tid >> 8;        // t-half (wave-uniform)
  const int q = q0 + lane;

  __shared__ float4 s_tb[NB * T];
  __shared__ int s_idv[NB * T];     // (valid<<8) | id
  __shared__ float s_rden[NB];      // 1/denom
  __shared__ float s_res[2 * 64 * RS];

  for (int i = tid; i < NB * T; i += 512) {
    int n = n0 + i / T;
    int t = i % T;
    int g = n * T + t;
    s_idv[i] = ((ovalid[g] == 0) ? (C - 1) : labels[g]) | (valid[g] << 8);
    s_tb[i] = ((const float4*)tboxes)[g];
  }
  if (tid < NB) {
    int n = n0 + tid;
    int s = 0;
    for (int t = 0; t < T; ++t) s += valid[n * T + t];
    s_rden[tid] = 1.f / (float)s;
  }
  __syncthreads();

  float acc = 0.f;
  const __hip_bfloat16* probs_base = P2 + q;
  const int t_begin = half * (T / 2);
  const int t_end = t_begin + (T / 2);

  for (int t = t_begin; t < t_end; ++t) {
    int pk = s_idv[sub * T + t];
    if (pk & 0x100) {  // wave-uniform: whole wave shares (n,t) -> no divergence
      float4 pb = ((const float4*)pred_boxes)[t * Q + q];
      float4 tb = s_tb[sub * T + t];
      int id = pk & 0xff;
      // Coalesced gather: 64 lanes -> 64 consecutive bf16 (one 128B line).
      float p = __bfloat162float(probs_base[(size_t)(t * C + id) * Q]);

      float l1 = 0.25f * (fabsf(pb.x - tb.x) + fabsf(pb.y - tb.y) +
                          fabsf(pb.z - tb.z) + fabsf(pb.w - tb.w));
      float px1 = pb.x - 0.5f * pb.z, py1 = pb.y - 0.5f * pb.w;
      float px2 = pb.x + 0.5f * pb.z, py2 = pb.y + 0.5f * pb.w;
      float tx1 = tb.x - 0.5f * tb.z, ty1 = tb.y - 0.5f * tb.w;
      float tx2 = tb.x + 0.5f * tb.z, ty2 = tb.y + 0.5f * tb.w;
      float iw = fmaxf(fminf(px2, tx2) - fmaxf(px1, tx1), 0.f);
      float ih = fmaxf(fminf(py2, ty2) - fmaxf(py1, ty1), 0.f);
      float inter = iw * ih;
      float uni = pb.z * pb.w + tb.z * tb.w - inter;
      acc += l1 - p - inter / uni;
    }
  }

  // Combine t-halves, then transpose through LDS for coalesced float4 stores.
  s_res[half * (64 * RS) + lane * RS + sub] = acc;
  __syncthreads();
  if (half == 0) {
    float tot = (acc + s_res[64 * RS + lane * RS + sub]) * s_rden[sub];
    s_res[lane * RS + sub] = tot;
  }
  __syncthreads();

  if (tid < 64) {
    float4 o;
    o.x = s_res[tid * RS + 0];
    o.y = s_res[tid * RS + 1];
    o.z = s_res[tid * RS + 2];
    o.w = s_res[tid * RS + 3];
    *(float4*)(out + (size_t)(q0 + tid) * N + n0) = o;
  }
}

extern "C" void kernel_launch(void* const* d_in, const int* in_sizes, int n_in,
                              void* d_out, int out_size, void* d_ws, size_t ws_size,
                              hipStream_t stream) {
  const float* logits = (const float*)d_in[0];
  const float* pboxes = (const float*)d_in[1];
  const int* labels = (const int*)d_in[2];
  const float* tboxes = (const float*)d_in[3];
  const int* valid = (const int*)d_in[4];
  const int* ovalid = (const int*)d_in[5];
  float* out = (float*)d_out;

  // Workspace: transposed bf16 probs P2[T][C][Q] = 36*42*2048*2 B = 6.2 MB.
  __hip_bfloat16* P2 = (__hip_bfloat16*)d_ws;

  dim3 g1(Q / 64, T);
  softmax_transpose_kernel<<<g1, 256, 0, stream>>>(logits, P2);

  dim3 g2(Q / 64, N / 4);
  cost_kernel<<<g2, 512, 0, stream>>>(P2, pboxes, labels, tboxes, valid, ovalid, out);
}